// Round 6
// baseline (189.822 us; speedup 1.0000x reference)
//
#include <hip/hip_runtime.h>

typedef __bf16 bf16_t;
typedef __bf16 bf16x4 __attribute__((ext_vector_type(4)));
typedef __bf16 bf16x8 __attribute__((ext_vector_type(8)));
typedef float f32x4 __attribute__((ext_vector_type(4)));
typedef unsigned int u32x2 __attribute__((ext_vector_type(2)));
typedef unsigned long long u64;

#define MFMA16(a, b, c) __builtin_amdgcn_mfma_f32_16x16x32_bf16((a), (b), (c), 0, 0, 0)

#define LDG2LDS16(g, l)                                                        \
    __builtin_amdgcn_global_load_lds(                                          \
        (const __attribute__((address_space(1))) void*)(g),                    \
        (__attribute__((address_space(3))) void*)(l), 16, 0, 0)

#if __has_builtin(__builtin_amdgcn_exp2f)
#define EXP2(x) __builtin_amdgcn_exp2f(x)
#else
#define EXP2(x) exp2f(x)
#endif

// load 8 consecutive fp32 as bf16x8
__device__ inline bf16x8 load8(const float* p) {
    const f32x4 a = *(const f32x4*)p;
    const f32x4 b = *(const f32x4*)(p + 4);
    bf16x8 r;
#pragma unroll
    for (int i = 0; i < 4; i++) { r[i] = (bf16_t)a[i]; r[4 + i] = (bf16_t)b[i]; }
    return r;
}

__device__ inline u32x2 as2(bf16x4 v) {
    u32x2 r;
    __builtin_memcpy(&r, &v, 8);
    return r;
}

// 8-byte cross-lane shuffle of a packed bf16x4 (fallback path)
__device__ inline bf16x4 shfl4(bf16x4 v, int src) {
    u64 x;
    __builtin_memcpy(&x, &v, 8);
    x = __shfl(x, src, 64);
    bf16x4 r;
    __builtin_memcpy(&r, &x, 8);
    return r;
}

// ---------------------------------------------------------------------------
// fp32 -> bf16 convert: hs (4194304 el) | wqkv (3145728 el) | wo (1048576 el)
// ---------------------------------------------------------------------------
__global__ __launch_bounds__(256) void convert_kernel(const float* __restrict__ hs,
                                                      const float* __restrict__ wqkv,
                                                      const float* __restrict__ wo,
                                                      bf16_t* __restrict__ outb) {
    const size_t c = ((size_t)blockIdx.x * 256 + threadIdx.x) * 8;
    const float* src;
    size_t off;
    if (c < 4194304) { src = hs; off = c; }
    else if (c < 7340032) { src = wqkv; off = c - 4194304; }
    else { src = wo; off = c - 7340032; }
    *(bf16x8*)(outb + c) = load8(src + off);
}

// ---------------------------------------------------------------------------
// K/V swizzled layouts (MFMA-fragment order -> attn loads are base+lane*16):
//   k_sw: ((bh*128 + t>>4)*2 + (d>>5))*512 + ((t&15)+16*((d&31)>>3))*8 + (d&7)
//   v_sw: ((bh*64 + t>>5)*4 + (d>>4))*512 + ((d&15)+16*((t&31)>>3))*8 + (t&7)
// ---------------------------------------------------------------------------

// ---------------------------------------------------------------------------
// GEMM, m97 skeleton with BK=64 (round 6): one stage + one __syncthreads pair
// per 64 K-elements (16 iterations) instead of 32 -> the per-iteration
// vmcnt(0)+barrier drain (the measured ~30% 2-phase stall; r3/r5 ruled out
// conflicts and LDS volume) amortizes 2x. LDS 32 KB/WG (BM=128) keeps
// 3 WGs/CU occupancy (m132's BK=128 regression was the 64KB/2-WG regime).
// T2 XOR swizzle at 8x16B slots, both-sides (rule 21): staging SOURCE slot =
// (tid&7)^(row&7) with linear LDS dest; fragment read slot = gslot^(lr&7).
// Measured conflict-free in rounds 2/3/5.
// ---------------------------------------------------------------------------
template <int MODE, int NDIM, int BM>
__global__ __launch_bounds__(256) void gemm_bt(const bf16_t* __restrict__ A,
                                               const bf16_t* __restrict__ B,
                                               float* __restrict__ outp,
                                               bf16_t* __restrict__ q_ws,
                                               bf16_t* __restrict__ k_ws,
                                               bf16_t* __restrict__ v_ws,
                                               const float* __restrict__ cosb,
                                               const float* __restrict__ sinb) {
    constexpr int K = 1024;
    constexpr int IM = BM / 32;
    __shared__ __align__(16) bf16_t As[BM * 64];
    __shared__ __align__(16) bf16_t Bs[128 * 64];

    const int tid = threadIdx.x;
    const int w = tid >> 6;
    const int lane = tid & 63;
    const int lr = lane & 15;
    const int quad = lane >> 4;
    const int m0 = blockIdx.y * BM;
    const int n0 = blockIdx.x * 128;
    const int wm = (w & 1) * (BM / 2);
    const int wn = (w >> 1) * 64;

    // Staging: thread t covers row (c*32 + t>>3), LDS 16B slot (t&7); LDS dest
    // is linear (global_load_lds), so SOURCE slot = (t&7) ^ (row&7).
    const int trow = tid >> 3;                    // 0..31
    const int slot = (tid & 7) ^ (trow & 7);
    const bf16_t* gA = A + (size_t)(m0 + trow) * K + slot * 8;
    const bf16_t* gB = B + (size_t)(n0 + trow) * K + slot * 8;
    bf16_t* lA = As + w * 512;                    // wave rows w*8..w*8+7
    bf16_t* lB = Bs + w * 512;

    // Fragment read: global slot (kh*4 + quad), swizzled byte offset:
    // o0 for kh=0, o0^64 for kh=1 (row&7 == lr&7 since wm,im*16 are mult of 8).
    const int o0 = (quad ^ (lr & 7)) * 16;
    const char* Ab = (const char*)As + (wm + lr) * 128;
    const char* Bb = (const char*)Bs + (wn + lr) * 128;

    f32x4 acc[IM][4] = {};

    for (int t = 0; t < 16; t++) {
        // stage K-tile t: A (BM/32 passes of 32 rows), B (4 passes)
#pragma unroll
        for (int c = 0; c < BM / 32; c++)
            LDG2LDS16(gA + (size_t)c * 32 * K + t * 64, lA + c * 2048);
#pragma unroll
        for (int c = 0; c < 4; c++)
            LDG2LDS16(gB + (size_t)c * 32 * K + t * 64, lB + c * 2048);
        __syncthreads();

#pragma unroll
        for (int kh = 0; kh < 2; kh++) {
            const int so = o0 ^ (kh * 64);
            bf16x8 af[IM], bfm[4];
#pragma unroll
            for (int im = 0; im < IM; im++)
                af[im] = *(const bf16x8*)(Ab + im * 2048 + so);
#pragma unroll
            for (int in = 0; in < 4; in++)
                bfm[in] = *(const bf16x8*)(Bb + in * 2048 + so);
#pragma unroll
            for (int im = 0; im < IM; im++)
#pragma unroll
                for (int in = 0; in < 4; in++)
                    acc[im][in] = MFMA16(af[im], bfm[in], acc[im][in]);
        }
        __syncthreads();
    }

    if constexpr (MODE == 0) {
#pragma unroll
        for (int im = 0; im < IM; im++)
#pragma unroll
            for (int in = 0; in < 4; in++)
#pragma unroll
                for (int r = 0; r < 4; r++) {
                    const int m = m0 + wm + im * 16 + quad * 4 + r;
                    const int n = n0 + wn + in * 16 + lr;
                    outp[(size_t)m * NDIM + n] = acc[im][in][r];
                }
    } else {
        const int j = (n0 + wn) >> 6;
        if (j < 32) {
            const bool isq = (j < 16);
            const float qs = 0.125f * 1.44269504089f;
#pragma unroll
            for (int im = 0; im < IM; im++) {
#pragma unroll
                for (int r = 0; r < 4; r++) {
                    const int m = m0 + wm + im * 16 + quad * 4 + r;
                    const int b = m >> 11;
                    const int t = m & 2047;
#pragma unroll
                    for (int in = 0; in < 2; in++) {
                        const int d = in * 16 + lr;
                        const float x1 = acc[im][in][r];
                        const float x2 = acc[im][in + 2][r];
                        const float c = cosb[t * 64 + d];
                        const float s = sinb[t * 64 + d];
                        float y1 = x1 * c - x2 * s;
                        float y2 = x2 * c + x1 * s;
                        if (isq) {
                            y1 *= qs; y2 *= qs;
                            const size_t base =
                                ((size_t)(b * 16 + j) * 2048 + t) * 64 + d;
                            q_ws[base] = (bf16_t)y1;
                            q_ws[base + 32] = (bf16_t)y2;
                        } else {
                            const int bh = b * 16 + (j - 16);
                            const size_t off =
                                ((size_t)(bh * 128 + (t >> 4)) * 2) * 512 +
                                ((t & 15) + (d >> 3) * 16) * 8 + (d & 7);
                            k_ws[off] = (bf16_t)y1;
                            k_ws[off + 512] = (bf16_t)y2;
                        }
                    }
                }
            }
        } else {
#pragma unroll
            for (int im = 0; im < IM; im++)
#pragma unroll
                for (int in = 0; in < 4; in++)
#pragma unroll
                    for (int r = 0; r < 4; r++) {
                        const int m = m0 + wm + im * 16 + quad * 4 + r;
                        const int b = m >> 11;
                        const int t = m & 2047;
                        const int d = in * 16 + lr;
                        const int bh = b * 16 + (j - 32);
                        const size_t off =
                            ((size_t)(bh * 64 + (t >> 5)) * 4 + (d >> 4)) * 512 +
                            ((d & 15) + ((t & 31) >> 3) * 16) * 8 + (t & 7);
                        v_ws[off] = (bf16_t)acc[im][in][r];
                    }
        }
    }
}

// ---------------------------------------------------------------------------
// One flash tile: 16 queries (this wave), keys 0..(qt+1)*64. Transposed-score,
// max-free, LDS-free. P C-layout -> PV B-fragment via 6 permlane-swaps per
// 32-key half (gfx950 v_permlane16/32_swap), falling back to ds_bpermute
// shuffles if the builtin is missing.
// ---------------------------------------------------------------------------
__device__ inline void flash_tile(int qt, int quad, int lr, int query,
                                  const bf16_t* __restrict__ kbase,
                                  const bf16_t* __restrict__ vbase,
                                  bf16x8 qlo, bf16x8 qhi,
                                  f32x4* o, float& lrun) {
    // prime K(0)
    bf16x8 kc[8];
#pragma unroll
    for (int n = 0; n < 4; n++) {
        kc[2 * n] = *(const bf16x8*)(kbase + (size_t)(n * 2) * 512);
        kc[2 * n + 1] = *(const bf16x8*)(kbase + (size_t)(n * 2 + 1) * 512);
    }

    for (int kb = 0; kb <= qt; kb++) {
        bf16x8 vv[2][4];
#pragma unroll
        for (int hh = 0; hh < 2; hh++)
#pragma unroll
            for (int n = 0; n < 4; n++)
                vv[hh][n] = *(const bf16x8*)(vbase +
                    (size_t)((kb * 2 + hh) * 4 + n) * 512);

        const int kbn = (kb < qt) ? kb + 1 : kb;
        bf16x8 kn[8];
#pragma unroll
        for (int n = 0; n < 4; n++) {
            kn[2 * n] = *(const bf16x8*)(kbase + (size_t)((kbn * 4 + n) * 2) * 512);
            kn[2 * n + 1] = *(const bf16x8*)(kbase + (size_t)((kbn * 4 + n) * 2 + 1) * 512);
        }

        const int u0 = kb * 64;
        f32x4 s[4];
#pragma unroll
        for (int n = 0; n < 4; n++) {
            const f32x4 z = {};
            s[n] = MFMA16(kc[2 * n], qlo, z);
            s[n] = MFMA16(kc[2 * n + 1], qhi, s[n]);
        }

        if (kb == qt) {  // diagonal 64-key block: causal mask (key > query)
#pragma unroll
            for (int n = 0; n < 4; n++)
#pragma unroll
                for (int r = 0; r < 4; r++)
                    if (u0 + n * 16 + quad * 4 + r > query) s[n][r] = -1e9f;
        }

        f32x4 p[4];
#pragma unroll
        for (int n = 0; n < 4; n++)
#pragma unroll
            for (int r = 0; r < 4; r++) p[n][r] = EXP2(s[n][r]);

        lrun += ((p[0][0] + p[0][1]) + (p[0][2] + p[0][3])) +
                ((p[1][0] + p[1][1]) + (p[1][2] + p[1][3])) +
                ((p[2][0] + p[2][1]) + (p[2][2] + p[2][3])) +
                ((p[3][0] + p[3][1]) + (p[3][2] + p[3][3]));

        bf16x4 pb[4];
#pragma unroll
        for (int n = 0; n < 4; n++)
#pragma unroll
            for (int r = 0; r < 4; r++) pb[n][r] = (bf16_t)p[n][r];

#pragma unroll
        for (int hh = 0; hh < 2; hh++) {  // 32-key halves
            bf16x8 pf;
#if __has_builtin(__builtin_amdgcn_permlane16_swap) && \
    __has_builtin(__builtin_amdgcn_permlane32_swap)
            const u32x2 P0 = as2(pb[2 * hh]);
            const u32x2 P1 = as2(pb[2 * hh + 1]);
            const u32x2 s1a = __builtin_amdgcn_permlane16_swap(P0[0], P0[1], false, false);
            const u32x2 s1b = __builtin_amdgcn_permlane16_swap(P1[0], P1[1], false, false);
            const u32x2 s2a = __builtin_amdgcn_permlane32_swap(s1a[0], s1b[0], false, false);
            const u32x2 s2b = __builtin_amdgcn_permlane32_swap(s1a[1], s1b[1], false, false);
            const u32x2 s3a = __builtin_amdgcn_permlane16_swap(s2a[0], s2a[1], false, false);
            const u32x2 s3b = __builtin_amdgcn_permlane16_swap(s2b[0], s2b[1], false, false);
            const unsigned pfd[4] = {s3a[0], s3a[1], s3b[0], s3b[1]};
            __builtin_memcpy(&pf, pfd, 16);
#else
            const int srcLow = ((quad & 1) << 5) + lr;
            const int srcHigh = srcLow + 16;
            const bool loSel = (quad < 2);
            const bf16x4 a0 = shfl4(pb[2 * hh], srcLow);
            const bf16x4 a1 = shfl4(pb[2 * hh + 1], srcLow);
            const bf16x4 b0 = shfl4(pb[2 * hh], srcHigh);
            const bf16x4 b1 = shfl4(pb[2 * hh + 1], srcHigh);
            const bf16x4 lo = loSel ? a0 : a1;
            const bf16x4 hi = loSel ? b0 : b1;
#pragma unroll
            for (int r = 0; r < 4; r++) { pf[r] = lo[r]; pf[4 + r] = hi[r]; }
#endif
#pragma unroll
            for (int n = 0; n < 4; n++)
                o[n] = MFMA16(vv[hh][n], pf, o[n]);
        }

#pragma unroll
        for (int i = 0; i < 8; i++) kc[i] = kn[i];
    }
}

// ---------------------------------------------------------------------------
// Flash attention, paired tiles for perfect load balance: 512 WGs, WG =
// (pr, bh) handles qt = pr AND qt = 31-pr -> every WG exactly 33 iterations,
// every CU identical (2 WGs x 33). 4 independent waves, no barriers, no LDS.
// ---------------------------------------------------------------------------
__global__ __launch_bounds__(256) void attn_kernel(const bf16_t* __restrict__ q_ws,
                                                   const bf16_t* __restrict__ k_ws,
                                                   const bf16_t* __restrict__ v_ws,
                                                   bf16_t* __restrict__ ctx) {
    const int tid = threadIdx.x;
    const int w = tid >> 6;
    const int lane = tid & 63;
    const int lr = lane & 15;
    const int quad = lane >> 4;
    const int bh = blockIdx.x & 31;
    const int pr = blockIdx.x >> 5;  // 0..15
    const int b = bh >> 4;
    const int hd = bh & 15;

    const bf16_t* kbase = k_ws + (size_t)bh * 131072 + lane * 8;
    const bf16_t* vbase = v_ws + (size_t)bh * 131072 + lane * 8;

#pragma unroll
    for (int half = 0; half < 2; half++) {
        const int qt = half ? (31 - pr) : pr;
        const int trow = qt * 64 + w * 16;
        const int query = trow + lr;

        const bf16_t* qb = q_ws + ((size_t)bh * 2048 + trow + lr) * 64 + quad * 8;
        const bf16x8 qlo = *(const bf16x8*)qb;
        const bf16x8 qhi = *(const bf16x8*)(qb + 32);

        f32x4 o[4] = {};
        float lrun = 0.0f;
        flash_tile(qt, quad, lr, query, kbase, vbase, qlo, qhi, o, lrun);

        lrun += __shfl_xor(lrun, 16);
        lrun += __shfl_xor(lrun, 32);

        const float inv = 1.0f / fmaxf(lrun, 1e-30f);
        const size_t base = ((size_t)b * 2048 + query) * 1024 + hd * 64 + quad * 4;
#pragma unroll
        for (int n = 0; n < 4; n++) {
            bf16x4 ob;
#pragma unroll
            for (int r = 0; r < 4; r++) ob[r] = (bf16_t)(o[n][r] * inv);
            *(bf16x4*)&ctx[base + n * 16] = ob;
        }
    }
}

// ---------------------------------------------------------------------------
// Launcher. Inputs fp32, output fp32.
// ws bytes: [0,8M) hs_b -> (after gemm1) ctx overlay | [8M,14M) wqkv_b |
//           [14M,16M) wo_b | [16M,24M) q | [24M,32M) k | [32M,40M) v.
// ---------------------------------------------------------------------------
extern "C" void kernel_launch(void* const* d_in, const int* in_sizes, int n_in,
                              void* d_out, int out_size, void* d_ws, size_t ws_size,
                              hipStream_t stream) {
    const float* hs = (const float*)d_in[0];
    const float* cosb = (const float*)d_in[1];
    const float* sinb = (const float*)d_in[2];
    const float* wqkv = (const float*)d_in[3];
    const float* wo = (const float*)d_in[4];
    float* out = (float*)d_out;

    char* ws = (char*)d_ws;
    bf16_t* hs_b = (bf16_t*)(ws);
    bf16_t* wqkv_b = hs_b + 4194304;
    bf16_t* wo_b = hs_b + 7340032;
    bf16_t* q_ws = (bf16_t*)(ws + (size_t)(16u << 20));
    bf16_t* k_ws = (bf16_t*)(ws + (size_t)(24u << 20));
    bf16_t* v_ws = (bf16_t*)(ws + (size_t)(32u << 20));
    bf16_t* ctx = (bf16_t*)(ws);  // overlays hs_b (dead after gemm1)

    const dim3 blk(256);

    // 0) fp32 -> bf16 convert (hs | wqkv | wo packed)
    convert_kernel<<<dim3(4096), blk, 0, stream>>>(hs, wqkv, wo, hs_b);

    // 1) QKV projection + fused RoPE + scatter: M=4096, N=3072, K=1024
    gemm_bt<1, 3072, 128><<<dim3(24, 32), blk, 0, stream>>>(
        hs_b, wqkv_b, nullptr, q_ws, k_ws, v_ws, cosb, sinb);

    // 2) Flash attention (paired tiles) -> ctx [B,T,1024] (bf16)
    attn_kernel<<<dim3(512), blk, 0, stream>>>(q_ws, k_ws, v_ws, ctx);

    // 3) Output projection: M=4096, N=1024, K=1024 (BM=64 -> 512 blocks)
    gemm_bt<0, 1024, 64><<<dim3(8, 64), blk, 0, stream>>>(
        ctx, wo_b, out, nullptr, nullptr, nullptr, nullptr, nullptr);
}

// Round 7
// 172.903 us; speedup vs baseline: 1.0979x; 1.0979x over previous
//
#include <hip/hip_runtime.h>

typedef __bf16 bf16_t;
typedef __bf16 bf16x4 __attribute__((ext_vector_type(4)));
typedef __bf16 bf16x8 __attribute__((ext_vector_type(8)));
typedef float f32x4 __attribute__((ext_vector_type(4)));
typedef unsigned int u32x2 __attribute__((ext_vector_type(2)));
typedef unsigned long long u64;

#define MFMA16(a, b, c) __builtin_amdgcn_mfma_f32_16x16x32_bf16((a), (b), (c), 0, 0, 0)

#define LDG2LDS16(g, l)                                                        \
    __builtin_amdgcn_global_load_lds(                                          \
        (const __attribute__((address_space(1))) void*)(g),                    \
        (__attribute__((address_space(3))) void*)(l), 16, 0, 0)

#if __has_builtin(__builtin_amdgcn_exp2f)
#define EXP2(x) __builtin_amdgcn_exp2f(x)
#else
#define EXP2(x) exp2f(x)
#endif

// load 8 consecutive fp32 as bf16x8
__device__ inline bf16x8 load8(const float* p) {
    const f32x4 a = *(const f32x4*)p;
    const f32x4 b = *(const f32x4*)(p + 4);
    bf16x8 r;
#pragma unroll
    for (int i = 0; i < 4; i++) { r[i] = (bf16_t)a[i]; r[4 + i] = (bf16_t)b[i]; }
    return r;
}

__device__ inline u32x2 as2(bf16x4 v) {
    u32x2 r;
    __builtin_memcpy(&r, &v, 8);
    return r;
}

// 8-byte cross-lane shuffle of a packed bf16x4 (fallback path)
__device__ inline bf16x4 shfl4(bf16x4 v, int src) {
    u64 x;
    __builtin_memcpy(&x, &v, 8);
    x = __shfl(x, src, 64);
    bf16x4 r;
    __builtin_memcpy(&r, &x, 8);
    return r;
}

// ---------------------------------------------------------------------------
// fp32 -> bf16 convert: hs (4194304 el) | wqkv (3145728 el) | wo (1048576 el)
// ---------------------------------------------------------------------------
__global__ __launch_bounds__(256) void convert_kernel(const float* __restrict__ hs,
                                                      const float* __restrict__ wqkv,
                                                      const float* __restrict__ wo,
                                                      bf16_t* __restrict__ outb) {
    const size_t c = ((size_t)blockIdx.x * 256 + threadIdx.x) * 8;
    const float* src;
    size_t off;
    if (c < 4194304) { src = hs; off = c; }
    else if (c < 7340032) { src = wqkv; off = c - 4194304; }
    else { src = wo; off = c - 7340032; }
    *(bf16x8*)(outb + c) = load8(src + off);
}

// ---------------------------------------------------------------------------
// K/V swizzled layouts (MFMA-fragment order -> attn loads are base+lane*16):
//   k_sw: ((bh*128 + t>>4)*2 + (d>>5))*512 + ((t&15)+16*((d&31)>>3))*8 + (d&7)
//   v_sw: ((bh*64 + t>>5)*4 + (d>>4))*512 + ((d&15)+16*((t&31)>>3))*8 + (t&7)
// NOTE: for a fixed 64-key tile kb, each of K/V occupies a CONTIGUOUS 4096-el
// (8 KB) region at base + kb*4096 -> stageable with 2 global_load_lds sweeps.
// ---------------------------------------------------------------------------

// ---------------------------------------------------------------------------
// GEMM (m97 structure, BK=32 — round-3 state, best measured 48.3us) + T2 XOR
// swizzle (conflicts measured 0).
// ---------------------------------------------------------------------------
template <int MODE, int NDIM, int BM>
__global__ __launch_bounds__(256) void gemm_bt(const bf16_t* __restrict__ A,
                                               const bf16_t* __restrict__ B,
                                               float* __restrict__ outp,
                                               bf16_t* __restrict__ q_ws,
                                               bf16_t* __restrict__ k_ws,
                                               bf16_t* __restrict__ v_ws,
                                               const float* __restrict__ cosb,
                                               const float* __restrict__ sinb) {
    constexpr int K = 1024;
    constexpr int IM = BM / 32;
    __shared__ __align__(16) bf16_t As[BM * 32];
    __shared__ __align__(16) bf16_t Bs[128 * 32];

    const int tid = threadIdx.x;
    const int w = tid >> 6;
    const int lane = tid & 63;
    const int lr = lane & 15;
    const int quad = lane >> 4;
    const int m0 = blockIdx.y * BM;
    const int n0 = blockIdx.x * 128;
    const int wm = (w & 1) * (BM / 2);
    const int wn = (w >> 1) * 64;

    const int srow = tid >> 2;
    // source slot pre-swizzled: slot ^ f(row), f(row) = (row>>1)&3
    const int skk = (((tid & 3) ^ ((tid >> 3) & 3)) * 8);
    const bf16_t* gA0 = A + (size_t)(m0 + srow) * K + skk;
    const bf16_t* gA1 = gA0 + (size_t)64 * K;
    const bf16_t* gB0 = B + (size_t)(n0 + srow) * K + skk;
    const bf16_t* gB1 = gB0 + (size_t)64 * K;
    bf16_t* lA0 = As + w * 512;
    bf16_t* lA1 = As + 2048 + w * 512;
    bf16_t* lB0 = Bs + w * 512;
    bf16_t* lB1 = Bs + 2048 + w * 512;

    // fragment-read slot: quad ^ f(row); row low bits = lr -> f = (lr>>1)&3
    const int qsw = (quad ^ ((lr >> 1) & 3)) * 8;

    f32x4 acc[IM][4] = {};

    for (int k0 = 0; k0 < K; k0 += 32) {
        LDG2LDS16(gA0 + k0, lA0);
        if constexpr (BM == 128) LDG2LDS16(gA1 + k0, lA1);
        LDG2LDS16(gB0 + k0, lB0);
        LDG2LDS16(gB1 + k0, lB1);
        __syncthreads();

        bf16x8 af[IM], bfm[4];
#pragma unroll
        for (int im = 0; im < IM; im++)
            af[im] = *(const bf16x8*)&As[(wm + im * 16 + lr) * 32 + qsw];
#pragma unroll
        for (int in = 0; in < 4; in++)
            bfm[in] = *(const bf16x8*)&Bs[(wn + in * 16 + lr) * 32 + qsw];
#pragma unroll
        for (int im = 0; im < IM; im++)
#pragma unroll
            for (int in = 0; in < 4; in++)
                acc[im][in] = MFMA16(af[im], bfm[in], acc[im][in]);
        __syncthreads();
    }

    if constexpr (MODE == 0) {
#pragma unroll
        for (int im = 0; im < IM; im++)
#pragma unroll
            for (int in = 0; in < 4; in++)
#pragma unroll
                for (int r = 0; r < 4; r++) {
                    const int m = m0 + wm + im * 16 + quad * 4 + r;
                    const int n = n0 + wn + in * 16 + lr;
                    outp[(size_t)m * NDIM + n] = acc[im][in][r];
                }
    } else {
        const int j = (n0 + wn) >> 6;
        if (j < 32) {
            const bool isq = (j < 16);
            const float qs = 0.125f * 1.44269504089f;
#pragma unroll
            for (int im = 0; im < IM; im++) {
#pragma unroll
                for (int r = 0; r < 4; r++) {
                    const int m = m0 + wm + im * 16 + quad * 4 + r;
                    const int b = m >> 11;
                    const int t = m & 2047;
#pragma unroll
                    for (int in = 0; in < 2; in++) {
                        const int d = in * 16 + lr;
                        const float x1 = acc[im][in][r];
                        const float x2 = acc[im][in + 2][r];
                        const float c = cosb[t * 64 + d];
                        const float s = sinb[t * 64 + d];
                        float y1 = x1 * c - x2 * s;
                        float y2 = x2 * c + x1 * s;
                        if (isq) {
                            y1 *= qs; y2 *= qs;
                            const size_t base =
                                ((size_t)(b * 16 + j) * 2048 + t) * 64 + d;
                            q_ws[base] = (bf16_t)y1;
                            q_ws[base + 32] = (bf16_t)y2;
                        } else {
                            const int bh = b * 16 + (j - 16);
                            const size_t off =
                                ((size_t)(bh * 128 + (t >> 4)) * 2) * 512 +
                                ((t & 15) + (d >> 3) * 16) * 8 + (d & 7);
                            k_ws[off] = (bf16_t)y1;
                            k_ws[off + 512] = (bf16_t)y2;
                        }
                    }
                }
            }
        } else {
#pragma unroll
            for (int im = 0; im < IM; im++)
#pragma unroll
                for (int in = 0; in < 4; in++)
#pragma unroll
                    for (int r = 0; r < 4; r++) {
                        const int m = m0 + wm + im * 16 + quad * 4 + r;
                        const int b = m >> 11;
                        const int t = m & 2047;
                        const int d = in * 16 + lr;
                        const int bh = b * 16 + (j - 32);
                        const size_t off =
                            ((size_t)(bh * 64 + (t >> 5)) * 4 + (d >> 4)) * 512 +
                            ((d & 15) + ((t & 31) >> 3) * 16) * 8 + (t & 7);
                        v_ws[off] = (bf16_t)acc[im][in][r];
                    }
        }
    }
}

// ---------------------------------------------------------------------------
// Flash attention (round 7): K/V tiles staged in LDS once per WG and shared by
// all 4 waves (they consume IDENTICAL tiles -> 4x cut of the L2 streaming
// traffic that bounds the kernel). Double-buffered, one barrier per tile,
// r2/r5-verified wait shape: stage(kb+1) issued at loop top (other buffer),
// compute(kb), then lgkmcnt(0)+vmcnt(0)+s_barrier — each wave waits its own
// stage loads pre-barrier, so post-barrier the whole tile is visible, and all
// reads of buf are done before it is overwritten next iteration.
// Math, P->PV permlane algebra, masking, outputs: unchanged from baseline.
// ---------------------------------------------------------------------------
__global__ __launch_bounds__(256) void attn_kernel(const bf16_t* __restrict__ q_ws,
                                                   const bf16_t* __restrict__ k_ws,
                                                   const bf16_t* __restrict__ v_ws,
                                                   bf16_t* __restrict__ ctx) {
    __shared__ __align__(16) bf16_t Ks[2][4096];  // 2 x 8 KB
    __shared__ __align__(16) bf16_t Vs[2][4096];  // 2 x 8 KB

    const int tid = threadIdx.x;
    const int w = tid >> 6;
    const int lane = tid & 63;
    const int lr = lane & 15;
    const int quad = lane >> 4;
    const int bh = blockIdx.x & 31;
    const int pr = blockIdx.x >> 5;  // 0..15
    const int b = bh >> 4;
    const int hd = bh & 15;

    const bf16_t* kws = k_ws + (size_t)bh * 131072;
    const bf16_t* vws = v_ws + (size_t)bh * 131072;
    const int soff = w * 512 + lane * 8;  // per-lane element offset in a sweep
    const int lo8 = lane * 8;

    // stage one 64-key K+V tile (8 KB each) into buf: 4 global_load_lds calls
#define ASTAGE(kb, buf)                                                        \
    {                                                                          \
        LDG2LDS16(kws + (size_t)(kb) * 4096 + soff, &Ks[buf][w * 512]);        \
        LDG2LDS16(kws + (size_t)(kb) * 4096 + 2048 + soff,                     \
                  &Ks[buf][2048 + w * 512]);                                   \
        LDG2LDS16(vws + (size_t)(kb) * 4096 + soff, &Vs[buf][w * 512]);        \
        LDG2LDS16(vws + (size_t)(kb) * 4096 + 2048 + soff,                     \
                  &Vs[buf][2048 + w * 512]);                                   \
    }

#pragma unroll
    for (int half = 0; half < 2; half++) {
        const int qt = half ? (31 - pr) : pr;
        const int trow = qt * 64 + w * 16;
        const int query = trow + lr;

        const bf16_t* qb = q_ws + ((size_t)bh * 2048 + trow + lr) * 64 + quad * 8;
        const bf16x8 qlo = *(const bf16x8*)qb;
        const bf16x8 qhi = *(const bf16x8*)(qb + 32);

        f32x4 o[4] = {};
        float lrun = 0.0f;

        // prologue: stage tile 0
        ASTAGE(0, 0);
        asm volatile("s_waitcnt vmcnt(0)" ::: "memory");
        __builtin_amdgcn_s_barrier();
        asm volatile("" ::: "memory");

        for (int kb = 0; kb <= qt; kb++) {
            const int buf = kb & 1;
            if (kb < qt) ASTAGE(kb + 1, buf ^ 1);

            // ---- QK^T from LDS ----
            f32x4 s[4];
#pragma unroll
            for (int n = 0; n < 4; n++) {
                const bf16x8 k0 = *(const bf16x8*)&Ks[buf][(2 * n) * 512 + lo8];
                const bf16x8 k1 = *(const bf16x8*)&Ks[buf][(2 * n + 1) * 512 + lo8];
                const f32x4 z = {};
                s[n] = MFMA16(k0, qlo, z);
                s[n] = MFMA16(k1, qhi, s[n]);
            }

            const int u0 = kb * 64;
            if (kb == qt) {  // diagonal: causal mask (key > query)
#pragma unroll
                for (int n = 0; n < 4; n++)
#pragma unroll
                    for (int r = 0; r < 4; r++)
                        if (u0 + n * 16 + quad * 4 + r > query) s[n][r] = -1e9f;
            }

            f32x4 p[4];
#pragma unroll
            for (int n = 0; n < 4; n++)
#pragma unroll
                for (int r = 0; r < 4; r++) p[n][r] = EXP2(s[n][r]);

            lrun += ((p[0][0] + p[0][1]) + (p[0][2] + p[0][3])) +
                    ((p[1][0] + p[1][1]) + (p[1][2] + p[1][3])) +
                    ((p[2][0] + p[2][1]) + (p[2][2] + p[2][3])) +
                    ((p[3][0] + p[3][1]) + (p[3][2] + p[3][3]));

            bf16x4 pb[4];
#pragma unroll
            for (int n = 0; n < 4; n++)
#pragma unroll
                for (int r = 0; r < 4; r++) pb[n][r] = (bf16_t)p[n][r];

#pragma unroll
            for (int hh = 0; hh < 2; hh++) {  // 32-key halves
                bf16x8 pf;
#if __has_builtin(__builtin_amdgcn_permlane16_swap) && \
    __has_builtin(__builtin_amdgcn_permlane32_swap)
                const u32x2 P0 = as2(pb[2 * hh]);
                const u32x2 P1 = as2(pb[2 * hh + 1]);
                const u32x2 s1a = __builtin_amdgcn_permlane16_swap(P0[0], P0[1], false, false);
                const u32x2 s1b = __builtin_amdgcn_permlane16_swap(P1[0], P1[1], false, false);
                const u32x2 s2a = __builtin_amdgcn_permlane32_swap(s1a[0], s1b[0], false, false);
                const u32x2 s2b = __builtin_amdgcn_permlane32_swap(s1a[1], s1b[1], false, false);
                const u32x2 s3a = __builtin_amdgcn_permlane16_swap(s2a[0], s2a[1], false, false);
                const u32x2 s3b = __builtin_amdgcn_permlane16_swap(s2b[0], s2b[1], false, false);
                const unsigned pfd[4] = {s3a[0], s3a[1], s3b[0], s3b[1]};
                __builtin_memcpy(&pf, pfd, 16);
#else
                const int srcLow = ((quad & 1) << 5) + lr;
                const int srcHigh = srcLow + 16;
                const bool loSel = (quad < 2);
                const bf16x4 a0 = shfl4(pb[2 * hh], srcLow);
                const bf16x4 a1 = shfl4(pb[2 * hh + 1], srcLow);
                const bf16x4 b0 = shfl4(pb[2 * hh], srcHigh);
                const bf16x4 b1 = shfl4(pb[2 * hh + 1], srcHigh);
                const bf16x4 lo = loSel ? a0 : a1;
                const bf16x4 hi = loSel ? b0 : b1;
#pragma unroll
                for (int r = 0; r < 4; r++) { pf[r] = lo[r]; pf[4 + r] = hi[r]; }
#endif
#pragma unroll
                for (int n = 0; n < 4; n++) {
                    const bf16x8 vvf =
                        *(const bf16x8*)&Vs[buf][(hh * 4 + n) * 512 + lo8];
                    o[n] = MFMA16(vvf, pf, o[n]);
                }
            }

            // all LDS reads of buf done; this wave's stage loads landed
            asm volatile("s_waitcnt lgkmcnt(0) vmcnt(0)" ::: "memory");
            __builtin_amdgcn_s_barrier();
            asm volatile("" ::: "memory");
        }

        lrun += __shfl_xor(lrun, 16);
        lrun += __shfl_xor(lrun, 32);

        const float inv = 1.0f / fmaxf(lrun, 1e-30f);
        const size_t base = ((size_t)b * 2048 + query) * 1024 + hd * 64 + quad * 4;
#pragma unroll
        for (int n = 0; n < 4; n++) {
            bf16x4 ob;
#pragma unroll
            for (int r = 0; r < 4; r++) ob[r] = (bf16_t)(o[n][r] * inv);
            *(bf16x4*)&ctx[base + n * 16] = ob;
        }
    }
#undef ASTAGE
}

// ---------------------------------------------------------------------------
// Launcher. Inputs fp32, output fp32.
// ws bytes: [0,8M) hs_b -> (after gemm1) ctx overlay | [8M,14M) wqkv_b |
//           [14M,16M) wo_b | [16M,24M) q | [24M,32M) k | [32M,40M) v.
// ---------------------------------------------------------------------------
extern "C" void kernel_launch(void* const* d_in, const int* in_sizes, int n_in,
                              void* d_out, int out_size, void* d_ws, size_t ws_size,
                              hipStream_t stream) {
    const float* hs = (const float*)d_in[0];
    const float* cosb = (const float*)d_in[1];
    const float* sinb = (const float*)d_in[2];
    const float* wqkv = (const float*)d_in[3];
    const float* wo = (const float*)d_in[4];
    float* out = (float*)d_out;

    char* ws = (char*)d_ws;
    bf16_t* hs_b = (bf16_t*)(ws);
    bf16_t* wqkv_b = hs_b + 4194304;
    bf16_t* wo_b = hs_b + 7340032;
    bf16_t* q_ws = (bf16_t*)(ws + (size_t)(16u << 20));
    bf16_t* k_ws = (bf16_t*)(ws + (size_t)(24u << 20));
    bf16_t* v_ws = (bf16_t*)(ws + (size_t)(32u << 20));
    bf16_t* ctx = (bf16_t*)(ws);  // overlays hs_b (dead after gemm1)

    const dim3 blk(256);

    // 0) fp32 -> bf16 convert (hs | wqkv | wo packed)
    convert_kernel<<<dim3(4096), blk, 0, stream>>>(hs, wqkv, wo, hs_b);

    // 1) QKV projection + fused RoPE + scatter: M=4096, N=3072, K=1024
    gemm_bt<1, 3072, 128><<<dim3(24, 32), blk, 0, stream>>>(
        hs_b, wqkv_b, nullptr, q_ws, k_ws, v_ws, cosb, sinb);

    // 2) Flash attention (paired tiles, LDS-shared K/V) -> ctx (bf16)
    attn_kernel<<<dim3(512), blk, 0, stream>>>(q_ws, k_ws, v_ws, ctx);

    // 3) Output projection: M=4096, N=1024, K=1024 (BM=64 -> 512 blocks)
    gemm_bt<0, 1024, 64><<<dim3(8, 64), blk, 0, stream>>>(
        ctx, wo_b, out, nullptr, nullptr, nullptr, nullptr, nullptr);
}